// Round 3
// baseline (108.247 us; speedup 1.0000x reference)
//
#include <hip/hip_runtime.h>
#include <hip/hip_fp16.h>

#define B_SZ    16384
#define NNZ_PER 32
#define F_DIM   768
#define H_DIM   512

typedef unsigned int  uint32;
typedef unsigned long long uint64;
typedef unsigned char uchar;

// ---------------------------------------------------------------------------
// fp32 -> fp8 e5m2 (RNE): e5m2 is the top byte of fp16. Decode (byte<<8) is
// exact fp16. Weights ~N(0,0.02): no overflow/subnormal trouble.
// ---------------------------------------------------------------------------
__device__ inline uchar f32_to_e5m2(float x) {
    __half h = __float2half_rn(x);
    unsigned short hb = *(unsigned short*)&h;
    unsigned short lsb = (hb >> 8) & 1;
    hb = (unsigned short)(hb + 0x7F + lsb);   // RNE into top 8 bits
    return (uchar)(hb >> 8);
}

__global__ __launch_bounds__(256) void transpose_convert(
    const float* __restrict__ W, uchar* __restrict__ Wt8)
{
    __shared__ float tile[32][33];
    const int f0 = blockIdx.x * 32;
    const int h0 = blockIdx.y * 32;
    const int tx = threadIdx.x;
    const int ty = threadIdx.y;

#pragma unroll
    for (int i = 0; i < 32; i += 8)
        tile[ty + i][tx] = W[(h0 + ty + i) * F_DIM + f0 + tx];
    __syncthreads();
#pragma unroll
    for (int i = 0; i < 32; i += 8)
        Wt8[(size_t)(f0 + ty + i) * H_DIM + h0 + tx] = f32_to_e5m2(tile[tx][ty + i]);
}

// ---------------------------------------------------------------------------
// Main: 1 wave per position; lane owns h = lane*8 .. lane*8+7 for ALL
// features (so no cross-lane combine in the epilogue). Feature indices are
// wave-uniform -> readfirstlane into SGPRs: every weight-row gather is
// global_load_dwordx2 with SGPR base + one shared lane-offset VGPR (zero
// VALU address math, no LDS on the load critical path). Values staged in
// LDS as half2(v,v), parity-sorted, read back as broadcast ds_read_b128.
// fp16 accumulation kept as even/odd 16-long chains + fp32 combine to
// exactly preserve the R2 rounding profile (absmax must stay 0.00390625).
// ---------------------------------------------------------------------------
__global__ __launch_bounds__(256, 6) void nnue_fwd(
    const int*   __restrict__ stm_idx,
    const int*   __restrict__ nstm_idx,
    const float* __restrict__ stm_val,
    const float* __restrict__ nstm_val,
    const uchar* __restrict__ Wt8,        // [F][H] e5m2
    const float* __restrict__ b_ft,
    const float* __restrict__ W_out,
    const float* __restrict__ b_out,
    float* __restrict__ out)
{
    const int tid  = threadIdx.x;
    const int w    = tid >> 6;
    const int lane = tid & 63;
    const int b    = blockIdx.x * 4 + w;
    const int NNZ  = B_SZ * NNZ_PER;
    const int ub   = __builtin_amdgcn_readfirstlane(b) * NNZ_PER;

    // Values only: sv[w][side*32 + (k&1)*16 + (k>>1)] = half2(v,v)
    __shared__ uint32 sv[4][64];
    {
        const int k    = lane & 31;
        const int side = lane >> 5;
        float v = (lane < 32) ? stm_val[ub + k] : nstm_val[ub + k];
        __half2 vv = __float2half2_rn(v);
        sv[w][side * 32 + (k & 1) * 16 + (k >> 1)] = *(uint32*)&vv;
    }
    __syncthreads();

    // Wave-uniform feature indices -> SGPRs.
    int sf[32], nf[32];
#pragma unroll
    for (int k = 0; k < 32; ++k) {
        sf[k] = __builtin_amdgcn_readfirstlane(stm_idx [NNZ + ub + k]);
        nf[k] = __builtin_amdgcn_readfirstlane(nstm_idx[NNZ + ub + k]);
    }

    const uint32 selA = 0x01040004u;   // [0,b0,0,b1] -> half2(h0,h1)
    const uint32 selB = 0x03040204u;   // [0,b2,0,b3] -> half2(h2,h3)
    const char*  Wb   = (const char*)Wt8;
    const uint32 loff = (uint32)(lane << 3);   // 8 B per lane within a 512 B row

    __half2 z = __float2half2_rn(0.f);
    __half2 se[4] = {z,z,z,z}, so[4] = {z,z,z,z};   // stm even/odd chains
    __half2 ne[4] = {z,z,z,z}, no[4] = {z,z,z,z};   // nstm

    uint2 bufA[8], bufB[8];

    // Group g in [0,8): g<4 stm, else nstm. Within the group:
    // slot i<4  -> even chain j = 4*(g&3)+i  (original k = 8*(g&3)+2i)
    // slot i>=4 -> odd  chain j = 4*(g&3)+(i-4) (k = 8*(g&3)+2(i-4)+1)
#define LOAD_GROUP(g, BUF)                                                    \
    {                                                                         \
        const int* IDX = ((g) >= 4) ? nf : sf;                                \
        const int  gg  = (g) & 3;                                             \
        _Pragma("unroll")                                                     \
        for (int i = 0; i < 4; ++i) {                                         \
            BUF[i]     = *(const uint2*)(Wb + (((size_t)IDX[8*gg + 2*i    ]) << 9) + loff); \
            BUF[4 + i] = *(const uint2*)(Wb + (((size_t)IDX[8*gg + 2*i + 1]) << 9) + loff); \
        }                                                                     \
    }

#define FMA_GROUP(g, BUF, ACCE, ACCO)                                         \
    {                                                                         \
        const uint32* vb = &sv[w][((g) >= 4) ? 32 : 0];                       \
        uint4 ve = *(const uint4*)(vb + 4 * ((g) & 3));                       \
        uint4 vo = *(const uint4*)(vb + 16 + 4 * ((g) & 3));                  \
        uint32 va[8] = {ve.x, ve.y, ve.z, ve.w, vo.x, vo.y, vo.z, vo.w};      \
        _Pragma("unroll")                                                     \
        for (int i = 0; i < 8; ++i) {                                         \
            __half2* A = (i < 4) ? ACCE : ACCO;                               \
            __half2 vv = *(__half2*)&va[i];                                   \
            uint2 wv = BUF[i];                                                \
            uint32 p;                                                         \
            p = __builtin_amdgcn_perm(0u, wv.x, selA); A[0] = __hfma2(*(__half2*)&p, vv, A[0]); \
            p = __builtin_amdgcn_perm(0u, wv.x, selB); A[1] = __hfma2(*(__half2*)&p, vv, A[1]); \
            p = __builtin_amdgcn_perm(0u, wv.y, selA); A[2] = __hfma2(*(__half2*)&p, vv, A[2]); \
            p = __builtin_amdgcn_perm(0u, wv.y, selB); A[3] = __hfma2(*(__half2*)&p, vv, A[3]); \
        }                                                                     \
    }

    LOAD_GROUP(0, bufA);
    LOAD_GROUP(1, bufB);
    FMA_GROUP(0, bufA, se, so);  LOAD_GROUP(2, bufA);
    FMA_GROUP(1, bufB, se, so);  LOAD_GROUP(3, bufB);
    FMA_GROUP(2, bufA, se, so);  LOAD_GROUP(4, bufA);
    FMA_GROUP(3, bufB, se, so);  LOAD_GROUP(5, bufB);
    FMA_GROUP(4, bufA, ne, no);  LOAD_GROUP(6, bufA);
    FMA_GROUP(5, bufB, ne, no);  LOAD_GROUP(7, bufB);
    FMA_GROUP(6, bufA, ne, no);
    FMA_GROUP(7, bufB, ne, no);

#undef LOAD_GROUP
#undef FMA_GROUP

    // Epilogue: lane's 8 h are complete. fp32 even+odd combine (same
    // rounding as R2), bias, clamp, dual-side dot against W_out.
    const int hbase = lane << 3;
    float dot = 0.f;
#pragma unroll
    for (int q = 0; q < 4; ++q) {
        float s0 = __low2float(se[q])  + __low2float(so[q]);
        float s1 = __high2float(se[q]) + __high2float(so[q]);
        float n0 = __low2float(ne[q])  + __low2float(no[q]);
        float n1 = __high2float(ne[q]) + __high2float(no[q]);
        float b0 = b_ft[hbase + 2*q];
        float b1 = b_ft[hbase + 2*q + 1];
        float a;
        a = fminf(fmaxf(s0 + b0, 0.f), 1.f); dot += a * W_out[hbase + 2*q];
        a = fminf(fmaxf(s1 + b1, 0.f), 1.f); dot += a * W_out[hbase + 2*q + 1];
        a = fminf(fmaxf(n0 + b0, 0.f), 1.f); dot += a * W_out[H_DIM + hbase + 2*q];
        a = fminf(fmaxf(n1 + b1, 0.f), 1.f); dot += a * W_out[H_DIM + hbase + 2*q + 1];
    }

#pragma unroll
    for (int off = 32; off > 0; off >>= 1)
        dot += __shfl_xor(dot, off, 64);

    if (lane == 0)
        out[b] = 1.f / (1.f + expf(-(dot + b_out[0])));
}

extern "C" void kernel_launch(void* const* d_in, const int* in_sizes, int n_in,
                              void* d_out, int out_size, void* d_ws, size_t ws_size,
                              hipStream_t stream) {
    const int*   stm_idx  = (const int*)  d_in[0];
    const int*   nstm_idx = (const int*)  d_in[1];
    const float* stm_val  = (const float*)d_in[2];
    const float* nstm_val = (const float*)d_in[3];
    const float* W_ft     = (const float*)d_in[5];
    const float* b_ft     = (const float*)d_in[6];
    const float* W_out    = (const float*)d_in[7];
    const float* b_out    = (const float*)d_in[8];
    float*       out      = (float*)d_out;
    uchar*       Wt8      = (uchar*)d_ws;   // 384 KiB

    dim3 tb(32, 8);
    dim3 tg(F_DIM / 32, H_DIM / 32);
    transpose_convert<<<tg, tb, 0, stream>>>(W_ft, Wt8);

    nnue_fwd<<<B_SZ / 4, 256, 0, stream>>>(stm_idx, nstm_idx, stm_val, nstm_val,
                                           Wt8, b_ft, W_out, b_out, out);
}

// Round 4
// 100.757 us; speedup vs baseline: 1.0743x; 1.0743x over previous
//
#include <hip/hip_runtime.h>
#include <hip/hip_fp16.h>

#define B_SZ    16384
#define NNZ_PER 32
#define F_DIM   768
#define H_DIM   512

typedef unsigned int  uint32;
typedef unsigned long long uint64;
typedef unsigned char uchar;

// ---------------------------------------------------------------------------
// fp32 -> fp8 e5m2 (RNE): e5m2 is the top byte of fp16. Decode (byte<<8) is
// exact fp16. Weights ~N(0,0.02): no overflow/subnormal trouble.
// ---------------------------------------------------------------------------
__device__ inline uchar f32_to_e5m2(float x) {
    __half h = __float2half_rn(x);
    unsigned short hb = *(unsigned short*)&h;
    unsigned short lsb = (hb >> 8) & 1;
    hb = (unsigned short)(hb + 0x7F + lsb);   // RNE into top 8 bits
    return (uchar)(hb >> 8);
}

__global__ __launch_bounds__(256) void transpose_convert(
    const float* __restrict__ W, uchar* __restrict__ Wt8)
{
    __shared__ float tile[32][33];
    const int f0 = blockIdx.x * 32;
    const int h0 = blockIdx.y * 32;
    const int tx = threadIdx.x;
    const int ty = threadIdx.y;

#pragma unroll
    for (int i = 0; i < 32; i += 8)
        tile[ty + i][tx] = W[(h0 + ty + i) * F_DIM + f0 + tx];
    __syncthreads();
#pragma unroll
    for (int i = 0; i < 32; i += 8)
        Wt8[(size_t)(f0 + ty + i) * H_DIM + h0 + tx] = f32_to_e5m2(tile[tx][ty + i]);
}

// ---------------------------------------------------------------------------
// Main: R2 structure (1 wave/position, 8 groups x 4 uint4 gathers, double
// buffered) with the pipeline FORCED: sched_barrier(0) after each load
// group prevents the scheduler from sinking gathers to their consumers
// (R1/R3 showed VGPR_Count 32-36 => the coded double-buffer was being
// de-pipelined, exposing full L2 latency per group). Metadata split into
// f (addresses, read at load time) and v (half2 values, read at FMA time).
// Addressing is uniform-base + 32-bit voffset. No __syncthreads: each wave
// only touches its own sh[w] slice. Accumulation order is bit-identical
// to R2 (absmax must stay 0.00390625).
// ---------------------------------------------------------------------------
__global__ __launch_bounds__(256, 6) void nnue_fwd(
    const int*   __restrict__ stm_idx,
    const int*   __restrict__ nstm_idx,
    const float* __restrict__ stm_val,
    const float* __restrict__ nstm_val,
    const uchar* __restrict__ Wt8,        // [F][H] e5m2
    const float* __restrict__ b_ft,
    const float* __restrict__ W_out,
    const float* __restrict__ b_out,
    float* __restrict__ out)
{
    const int tid  = threadIdx.x;
    const int w    = tid >> 6;
    const int lane = tid & 63;
    const int half = lane >> 5;
    const int c    = lane & 31;
    const int b    = blockIdx.x * 4 + w;
    const int NNZ  = B_SZ * NNZ_PER;

    // Parity-sorted metadata, split arrays:
    // slot = (k&1)*32 + side*16 + (k>>1); side 0=stm 1=nstm.
    __shared__ uint32 shf[4][64];   // feature index
    __shared__ uint32 shv[4][64];   // half2(v,v)
    {
        const int base = b * NNZ_PER;
        const int k    = lane & 31;
        const int side = lane >> 5;
        int f; float v;
        if (side == 0) { f = stm_idx [NNZ + base + k]; v = stm_val [base + k]; }
        else           { f = nstm_idx[NNZ + base + k]; v = nstm_val[base + k]; }
        const int slot = (k & 1) * 32 + side * 16 + (k >> 1);
        __half2 vv = __float2half2_rn(v);
        shf[w][slot] = (uint32)f;
        shv[w][slot] = *(uint32*)&vv;
    }
    // Producer wave == consumer wave: lgkmcnt ordering suffices, no barrier.

    const uint32 selA = 0x01040004u;   // [0,b0,0,b1] -> half2(h0,h1)
    const uint32 selB = 0x03040204u;   // [0,b2,0,b3] -> half2(h2,h3)
    const uint32 coff = (uint32)c << 4;          // 16 B per c in a 512 B row
    const uint32* fm  = &shf[w][half * 32];
    const uint32* vm  = &shv[w][half * 32];

    __half2 z = __float2half2_rn(0.f);
    __half2 sa[8] = {z,z,z,z,z,z,z,z};
    __half2 na[8] = {z,z,z,z,z,z,z,z};

    uint4 bufA[4], bufB[4];

    // Group g (0..3 stm -> sa, 4..7 nstm -> na); features = slots 4*(g&3)..+3
    // of the group's quadrant. sched_barrier(0) pins the 4 gathers ABOVE all
    // following code so the double-buffer stays materialized in VGPRs.
#define LOAD_GROUP(g, BUF)                                                    \
    {                                                                         \
        uint4 ff = *(const uint4*)(fm + ((g) >= 4 ? 16 : 0) + 4 * ((g) & 3)); \
        BUF[0] = *(const uint4*)(Wt8 + ((ff.x << 9) + coff));                 \
        BUF[1] = *(const uint4*)(Wt8 + ((ff.y << 9) + coff));                 \
        BUF[2] = *(const uint4*)(Wt8 + ((ff.z << 9) + coff));                 \
        BUF[3] = *(const uint4*)(Wt8 + ((ff.w << 9) + coff));                 \
        __builtin_amdgcn_sched_barrier(0);                                    \
    }

#define FMA_GROUP(g, BUF, ACC)                                                \
    {                                                                         \
        uint4 vv4 = *(const uint4*)(vm + ((g) >= 4 ? 16 : 0) + 4 * ((g) & 3));\
        uint32 va[4] = {vv4.x, vv4.y, vv4.z, vv4.w};                          \
        _Pragma("unroll")                                                     \
        for (int i = 0; i < 4; ++i) {                                         \
            uint4 wv = BUF[i];                                                \
            __half2 vv = *(__half2*)&va[i];                                   \
            uint32 p;                                                         \
            p = __builtin_amdgcn_perm(0u, wv.x, selA); ACC[0] = __hfma2(*(__half2*)&p, vv, ACC[0]); \
            p = __builtin_amdgcn_perm(0u, wv.x, selB); ACC[1] = __hfma2(*(__half2*)&p, vv, ACC[1]); \
            p = __builtin_amdgcn_perm(0u, wv.y, selA); ACC[2] = __hfma2(*(__half2*)&p, vv, ACC[2]); \
            p = __builtin_amdgcn_perm(0u, wv.y, selB); ACC[3] = __hfma2(*(__half2*)&p, vv, ACC[3]); \
            p = __builtin_amdgcn_perm(0u, wv.z, selA); ACC[4] = __hfma2(*(__half2*)&p, vv, ACC[4]); \
            p = __builtin_amdgcn_perm(0u, wv.z, selB); ACC[5] = __hfma2(*(__half2*)&p, vv, ACC[5]); \
            p = __builtin_amdgcn_perm(0u, wv.w, selA); ACC[6] = __hfma2(*(__half2*)&p, vv, ACC[6]); \
            p = __builtin_amdgcn_perm(0u, wv.w, selB); ACC[7] = __hfma2(*(__half2*)&p, vv, ACC[7]); \
        }                                                                     \
    }

    LOAD_GROUP(0, bufA);
    LOAD_GROUP(1, bufB);
    FMA_GROUP(0, bufA, sa);  LOAD_GROUP(2, bufA);
    FMA_GROUP(1, bufB, sa);  LOAD_GROUP(3, bufB);
    FMA_GROUP(2, bufA, sa);  LOAD_GROUP(4, bufA);
    FMA_GROUP(3, bufB, sa);  LOAD_GROUP(5, bufB);
    FMA_GROUP(4, bufA, na);  LOAD_GROUP(6, bufA);
    FMA_GROUP(5, bufB, na);  LOAD_GROUP(7, bufB);
    FMA_GROUP(6, bufA, na);
    FMA_GROUP(7, bufB, na);

#undef LOAD_GROUP
#undef FMA_GROUP

    // Epilogue (identical numerics to R2): lane^32 holds the other feature
    // parity for the same h-range; half=0 lanes dot stm vs W_out[0:512),
    // half=1 nstm vs W_out[512:1024); full-wave reduce sums everything.
    const float4* b4 = (const float4*)(b_ft + c * 16);
    const float4* w4 = (const float4*)(W_out + half * H_DIM + c * 16);
    float4 bv[4]  = {b4[0], b4[1], b4[2], b4[3]};
    float4 wv4[4] = {w4[0], w4[1], w4[2], w4[3]};
    const float* bias = (const float*)bv;
    const float* wo   = (const float*)wv4;

    float dot = 0.f;
#pragma unroll
    for (int k = 0; k < 8; ++k) {
        int ms = *(int*)&sa[k];
        int mn = *(int*)&na[k];
        int os = __shfl_xor(ms, 32, 64);
        int on = __shfl_xor(mn, 32, 64);
        int mm = half ? mn : ms;
        int oo = half ? on : os;
        __half2 mh = *(__half2*)&mm;
        __half2 oh = *(__half2*)&oo;
        float h0 = __low2float(mh)  + __low2float(oh);
        float h1 = __high2float(mh) + __high2float(oh);
        float a0 = fminf(fmaxf(h0 + bias[2 * k],     0.f), 1.f);
        float a1 = fminf(fmaxf(h1 + bias[2 * k + 1], 0.f), 1.f);
        dot += a0 * wo[2 * k] + a1 * wo[2 * k + 1];
    }

#pragma unroll
    for (int off = 32; off > 0; off >>= 1)
        dot += __shfl_xor(dot, off, 64);

    if (lane == 0)
        out[b] = 1.f / (1.f + expf(-(dot + b_out[0])));
}

extern "C" void kernel_launch(void* const* d_in, const int* in_sizes, int n_in,
                              void* d_out, int out_size, void* d_ws, size_t ws_size,
                              hipStream_t stream) {
    const int*   stm_idx  = (const int*)  d_in[0];
    const int*   nstm_idx = (const int*)  d_in[1];
    const float* stm_val  = (const float*)d_in[2];
    const float* nstm_val = (const float*)d_in[3];
    const float* W_ft     = (const float*)d_in[5];
    const float* b_ft     = (const float*)d_in[6];
    const float* W_out    = (const float*)d_in[7];
    const float* b_out    = (const float*)d_in[8];
    float*       out      = (float*)d_out;
    uchar*       Wt8      = (uchar*)d_ws;   // 384 KiB

    dim3 tb(32, 8);
    dim3 tg(F_DIM / 32, H_DIM / 32);
    transpose_convert<<<tg, tb, 0, stream>>>(W_ft, Wt8);

    nnue_fwd<<<B_SZ / 4, 256, 0, stream>>>(stm_idx, nstm_idx, stm_val, nstm_val,
                                           Wt8, b_ft, W_out, b_out, out);
}